// Round 16
// baseline (134.625 us; speedup 1.0000x reference)
//
#include <hip/hip_runtime.h>
#include <math.h>

#define O_CH 32
#define I_CH 3
#define IH 512
#define IW 512
#define OH 510
#define OW 510
#define N_IMG 16
#define BANDS 43         // 12-row bands per image (last band partial)

typedef float v2f __attribute__((ext_vector_type(2)));
typedef float v4f __attribute__((ext_vector_type(4)));

// 16B store with 8B-guaranteed alignment (global_store_dwordx4 needs only
// dword alignment; memcpy lets clang emit one dwordx4).
__device__ __forceinline__ void store16(float* p, v4f v) {
  __builtin_memcpy((void*)p, &v, 16);
}

// R15 = R13 structure widened to 24 px/lane at UNCHANGED occupancy:
// lane owns rows (y,y+1,y+2) x cols {x0..x0+3} U {x0+256..+259}.
// Rationale: R4->R9 (8->16px) won 17us; R8/R10 only ever tested fewer px
// for more waves (lost). 16->24px at same 2 waves/SIMD amortizes per-o
// overhead (7 weight ds_reads, stores, ptr bumps) over 1.5x px and cuts
// window-load instrs 33% (688 blocks vs 1024). VGPR ~250 < 256 keeps 2
// waves/SIMD. unroll 1: R14 proved o-boundary LDS stalls are negligible.
// Laws: all 32 o per register window (R6); pk-FMA (L,R) pair axis (R9);
// sequential phase-aligned o (R11); NO min-waves launch_bounds (R5/R7);
// regular stores (R3); fused weight-gen (R12); store16 everywhere (R13).
// XCD chunk swizzle: 688 blocks = 8 x 86, bijective, ~2 images/XCD.
__global__ __launch_bounds__(256) void gabor_conv_kernel(
    const float* __restrict__ in,
    const float* __restrict__ freq, const float* __restrict__ theta,
    const float* __restrict__ psi, const float* __restrict__ sigma,
    float* __restrict__ out) {
  __shared__ float sW[O_CH][28];   // 27 weights + pad, 7x float4 per o

  const int tid = threadIdx.x;
  // Compute all O*I*9 = 864 weights in-block (exact reference math, PI=3.14)
  for (int i = tid; i < O_CH * I_CH * 9; i += 256) {
    int o = i / 27;
    int rem = i % 27;            // rem = c*9 + kh*3 + kw
    int kh = (rem / 3) % 3;
    int kw = rem % 3;
    // linspace(-ceil(3/2)+1, ceil(3/2), 3) = {-1, 0.5, 2}
    float x = (kw == 0) ? -1.0f : (kw == 1 ? 0.5f : 2.0f);
    float y = (kh == 0) ? -1.0f : (kh == 1 ? 0.5f : 2.0f);
    int pi = o * I_CH + rem / 9; // (O,I) parameter index
    float th = theta[pi], f = freq[pi], p = psi[pi], s = sigma[pi];
    float ct = cosf(th), st = sinf(th);
    float rotx = x * ct + y * st;
    float roty = -x * st + y * ct;
    float se = s + 0.001f;
    float g = expf(-0.5f * (rotx * rotx + roty * roty) / (se * se));
    g *= cosf(f * rotx + p);
    g /= (2.0f * 3.14f * s * s);   // reference uses PI = 3.14 exactly
    sW[o][rem] = g;
  }
  if (tid < O_CH) sW[tid][27] = 0.0f;   // pad (read by b128, never used)
  __syncthreads();

  const int wave = tid >> 6;   // 0..3
  const int lane = tid & 63;

  // bijective chunked XCD swizzle: 688 blocks, 86 per XCD
  const int bid = blockIdx.x;
  const int nid = (bid & 7) * 86 + (bid >> 3);
  const int n    = nid / BANDS;            // image 0..15
  const int band = nid % BANDS;            // 12-row band 0..42
  const int y    = band * 12 + wave * 3;   // this wave's first output row
  if (y >= OH) return;   // band 42 waves 2,3 (y>=510); else y<=507, y+4<=511

  const int x0 = lane * 4;                 // L px x0..x0+3; R px +256
  const float* inN = in + (size_t)n * (I_CH * IH * IW);

  // Window as (L,R) column pairs: 3 ch x 5 rows x 6 cols = 90 v2f (180 regs)
  v2f P[I_CH][5][6];
#pragma unroll
  for (int c = 0; c < I_CH; ++c) {
#pragma unroll
    for (int rw = 0; rw < 5; ++rw) {
      const float* rowp = inN + ((size_t)c * IH + y + rw) * IW;
      v4f LA = *(const v4f*)&rowp[x0];          // cols x0..x0+3 (16B aligned)
      v2f LB = *(const v2f*)&rowp[x0 + 4];      // cols x0+4,x0+5
      v4f RA = *(const v4f*)&rowp[x0 + 256];    // cols x0+256..+259
      int xc = x0 + 260; if (xc > IW - 2) xc = IW - 2;  // lane63: 512 -> 510
      v2f RB = *(const v2f*)&rowp[xc];
      P[c][rw][0] = (v2f){LA.x, RA.x};
      P[c][rw][1] = (v2f){LA.y, RA.y};
      P[c][rw][2] = (v2f){LA.z, RA.z};
      P[c][rw][3] = (v2f){LA.w, RA.w};
      P[c][rw][4] = (v2f){LB.x, RB.x};
      P[c][rw][5] = (v2f){LB.y, RB.y};
    }
  }

  const bool full = (lane != 63);   // lane63 R px 510,511 are OOB
  float* op = out + (((size_t)n * O_CH * OH) + y) * OW + x0;  // o=0, row y, L

#pragma unroll 1
  for (int o = 0; o < O_CH; ++o) {
    float wq[28];
#pragma unroll
    for (int k = 0; k < 7; ++k) {            // 7 broadcast ds_read_b128
      v4f t = *(const v4f*)&sW[o][k * 4];
      wq[4 * k + 0] = t.x; wq[4 * k + 1] = t.y;
      wq[4 * k + 2] = t.z; wq[4 * k + 3] = t.w;
    }
    v2f a0[4], a1[4], a2[4];
#pragma unroll
    for (int j = 0; j < 4; ++j) {
      a0[j] = (v2f){0.f, 0.f}; a1[j] = (v2f){0.f, 0.f}; a2[j] = (v2f){0.f, 0.f};
    }
#pragma unroll
    for (int c = 0; c < I_CH; ++c) {
#pragma unroll
      for (int kh = 0; kh < 3; ++kh) {
#pragma unroll
        for (int kw = 0; kw < 3; ++kw) {
          float w = wq[c * 9 + kh * 3 + kw];
          v2f wv = (v2f){w, w};
#pragma unroll
          for (int j = 0; j < 4; ++j) {      // 12 v_pk_fma_f32 per tap
            a0[j] = __builtin_elementwise_fma(P[c][kh + 0][kw + j], wv, a0[j]);
            a1[j] = __builtin_elementwise_fma(P[c][kh + 1][kw + j], wv, a1[j]);
            a2[j] = __builtin_elementwise_fma(P[c][kh + 2][kw + j], wv, a2[j]);
          }
        }
      }
    }
    // unpack (L,R) pairs into row-contiguous quads; all stores 8B-aligned min
    v4f L0 = (v4f){a0[0].x, a0[1].x, a0[2].x, a0[3].x};
    v4f R0 = (v4f){a0[0].y, a0[1].y, a0[2].y, a0[3].y};
    v4f L1 = (v4f){a1[0].x, a1[1].x, a1[2].x, a1[3].x};
    v4f R1 = (v4f){a1[0].y, a1[1].y, a1[2].y, a1[3].y};
    v4f L2 = (v4f){a2[0].x, a2[1].x, a2[2].x, a2[3].x};
    v4f R2 = (v4f){a2[0].y, a2[1].y, a2[2].y, a2[3].y};
    store16(op, L0);
    store16(op + OW, L1);
    store16(op + 2 * OW, L2);
    if (full) {
      store16(op + 256, R0);
      store16(op + OW + 256, R1);
      store16(op + 2 * OW + 256, R2);
    } else {
      *(v2f*)(op + 256)          = (v2f){R0.x, R0.y};   // px 508,509
      *(v2f*)(op + OW + 256)     = (v2f){R1.x, R1.y};
      *(v2f*)(op + 2 * OW + 256) = (v2f){R2.x, R2.y};
    }
    op += (size_t)(OH * OW);
  }
}

extern "C" void kernel_launch(void* const* d_in, const int* in_sizes, int n_in,
                              void* d_out, int out_size, void* d_ws, size_t ws_size,
                              hipStream_t stream) {
  const float* img   = (const float*)d_in[0];
  const float* freq  = (const float*)d_in[1];
  const float* theta = (const float*)d_in[2];
  const float* psi   = (const float*)d_in[3];
  const float* sigma = (const float*)d_in[4];
  float* outp = (float*)d_out;

  dim3 grid(N_IMG * BANDS);   // 688 blocks; block = 12 rows (4 waves x 3 rows)
  gabor_conv_kernel<<<grid, dim3(256), 0, stream>>>(img, freq, theta, psi,
                                                    sigma, outp);
}

// Round 17
// 127.122 us; speedup vs baseline: 1.0590x; 1.0590x over previous
//
#include <hip/hip_runtime.h>
#include <math.h>

#define O_CH 32
#define I_CH 3
#define IH 512
#define IW 512
#define OH 510
#define OW 510
#define N_IMG 16

typedef float v2f __attribute__((ext_vector_type(2)));
typedef float v4f __attribute__((ext_vector_type(4)));

// 16B store with only 8B-guaranteed alignment: CDNA global_store_dwordx4
// needs only dword alignment; __builtin_memcpy lets clang emit one dwordx4
// instead of 2x dwordx2 (odd rows: (510y+x0)%4==2).
__device__ __forceinline__ void store16(float* p, v4f v) {
  __builtin_memcpy((void*)p, &v, 16);
}

// FINAL structure (R13 = best measured, 125.8us). Ledger of laws:
// - all 32 o per register-held window (R6: one-o-per-block costs 2.6x)
// - 16 px/lane, v_pk_fma_f32 (L,R) pair axis, mov-free tap pairs
//   (bracketed: 8px=149, 16px=125.8, 24px=134.6)
// - NO min-waves launch_bounds (R5/R7: allocator spills window, 7-20x FETCH)
// - regular stores (R3: nontemporal bypasses L2 merge, 2x WRITE_SIZE)
// - sequential phase-aligned o-loop (R11: stagger spreads L2 write set)
// - fused in-block weight-gen (R12: -5us vs separate kernel + d_ws trip)
// - single dwordx4 per row-store (R13), unroll 2 (one level of acc
//   rotation decouples stores from next FMA burst; deeper = VGPR cliff)
// Residual vs 77us write-floor is store-BW + partially-overlapped VALU,
// with all overlap levers measured null/negative.
// XCD chunk swizzle: 1024 blocks, q=128 = exactly 2 images per XCD.
__global__ __launch_bounds__(256) void gabor_conv_kernel(
    const float* __restrict__ in,
    const float* __restrict__ freq, const float* __restrict__ theta,
    const float* __restrict__ psi, const float* __restrict__ sigma,
    float* __restrict__ out) {
  __shared__ float sW[O_CH][28];   // 27 weights + pad, 7x float4 per o

  const int tid = threadIdx.x;
  // Compute all O*I*9 = 864 weights in-block (exact reference math, PI=3.14)
  for (int i = tid; i < O_CH * I_CH * 9; i += 256) {
    int o = i / 27;
    int rem = i % 27;            // rem = c*9 + kh*3 + kw
    int kh = (rem / 3) % 3;
    int kw = rem % 3;
    // linspace(-ceil(3/2)+1, ceil(3/2), 3) = {-1, 0.5, 2}
    float x = (kw == 0) ? -1.0f : (kw == 1 ? 0.5f : 2.0f);
    float y = (kh == 0) ? -1.0f : (kh == 1 ? 0.5f : 2.0f);
    int pi = o * I_CH + rem / 9; // (O,I) parameter index
    float th = theta[pi], f = freq[pi], p = psi[pi], s = sigma[pi];
    float ct = cosf(th), st = sinf(th);
    float rotx = x * ct + y * st;
    float roty = -x * st + y * ct;
    float se = s + 0.001f;
    float g = expf(-0.5f * (rotx * rotx + roty * roty) / (se * se));
    g *= cosf(f * rotx + p);
    g /= (2.0f * 3.14f * s * s);   // reference uses PI = 3.14 exactly
    sW[o][rem] = g;
  }
  if (tid < O_CH) sW[tid][27] = 0.0f;   // pad (read by b128, never used)
  __syncthreads();

  const int wave = tid >> 6;   // 0..3
  const int lane = tid & 63;

  // bijective chunked XCD swizzle: 1024 blocks, 128 per XCD (= 2 images)
  const int bid = blockIdx.x;
  const int nid = (bid & 7) * 128 + (bid >> 3);
  const int n = nid >> 6;                  // image 0..15
  const int y = (nid & 63) * 8 + wave * 2; // even top row of this wave's pair
  if (y + 1 >= OH) return;                 // only tail-block wave 3 (y=510)

  const int x0 = lane * 4;                 // L px x0..x0+3; R px +256
  const float* inN = in + (size_t)n * (I_CH * IH * IW);

  // Window as (L,R) column pairs: 3 ch x 4 rows x 6 cols = 72 v2f
  v2f P[I_CH][4][6];
#pragma unroll
  for (int c = 0; c < I_CH; ++c) {
#pragma unroll
    for (int rw = 0; rw < 4; ++rw) {
      const float* rowp = inN + ((size_t)c * IH + y + rw) * IW;
      v4f LA = *(const v4f*)&rowp[x0];          // cols x0..x0+3 (16B aligned)
      v2f LB = *(const v2f*)&rowp[x0 + 4];      // cols x0+4,x0+5
      v4f RA = *(const v4f*)&rowp[x0 + 256];    // cols x0+256..+259
      int xc = x0 + 260; if (xc > IW - 2) xc = IW - 2;  // lane63: 512 -> 510
      v2f RB = *(const v2f*)&rowp[xc];
      P[c][rw][0] = (v2f){LA.x, RA.x};
      P[c][rw][1] = (v2f){LA.y, RA.y};
      P[c][rw][2] = (v2f){LA.z, RA.z};
      P[c][rw][3] = (v2f){LA.w, RA.w};
      P[c][rw][4] = (v2f){LB.x, RB.x};
      P[c][rw][5] = (v2f){LB.y, RB.y};
    }
  }

  const bool full = (lane != 63);   // lane63 R px 510,511 are OOB
  float* op = out + (((size_t)n * O_CH * OH) + y) * OW + x0;  // o=0, row y, L

#pragma unroll 2
  for (int o = 0; o < O_CH; ++o) {
    float wq[28];
#pragma unroll
    for (int k = 0; k < 7; ++k) {            // 7 broadcast ds_read_b128
      v4f t = *(const v4f*)&sW[o][k * 4];
      wq[4 * k + 0] = t.x; wq[4 * k + 1] = t.y;
      wq[4 * k + 2] = t.z; wq[4 * k + 3] = t.w;
    }
    v2f a0[4], a1[4];
#pragma unroll
    for (int j = 0; j < 4; ++j) { a0[j] = (v2f){0.f, 0.f}; a1[j] = (v2f){0.f, 0.f}; }
#pragma unroll
    for (int c = 0; c < I_CH; ++c) {
#pragma unroll
      for (int kh = 0; kh < 3; ++kh) {
#pragma unroll
        for (int kw = 0; kw < 3; ++kw) {
          float w = wq[c * 9 + kh * 3 + kw];
          v2f wv = (v2f){w, w};
#pragma unroll
          for (int j = 0; j < 4; ++j) {      // 8 v_pk_fma_f32 per tap
            a0[j] = __builtin_elementwise_fma(P[c][kh + 0][kw + j], wv, a0[j]);
            a1[j] = __builtin_elementwise_fma(P[c][kh + 1][kw + j], wv, a1[j]);
          }
        }
      }
    }
    // unpack (L,R) pairs into row-contiguous quads
    v4f L0 = (v4f){a0[0].x, a0[1].x, a0[2].x, a0[3].x};
    v4f R0 = (v4f){a0[0].y, a0[1].y, a0[2].y, a0[3].y};
    v4f L1 = (v4f){a1[0].x, a1[1].x, a1[2].x, a1[3].x};
    v4f R1 = (v4f){a1[0].y, a1[1].y, a1[2].y, a1[3].y};
    // every row-store = one dwordx4 (odd rows align-8 via store16)
    store16(op, L0);
    store16(op + OW, L1);
    if (full) {
      store16(op + 256, R0);
      store16(op + OW + 256, R1);
    } else {
      *(v2f*)(op + 256)      = (v2f){R0.x, R0.y};   // px 508,509
      *(v2f*)(op + OW + 256) = (v2f){R1.x, R1.y};
    }
    op += (size_t)(OH * OW);
  }
}

extern "C" void kernel_launch(void* const* d_in, const int* in_sizes, int n_in,
                              void* d_out, int out_size, void* d_ws, size_t ws_size,
                              hipStream_t stream) {
  const float* img   = (const float*)d_in[0];
  const float* freq  = (const float*)d_in[1];
  const float* theta = (const float*)d_in[2];
  const float* psi   = (const float*)d_in[3];
  const float* sigma = (const float*)d_in[4];
  float* outp = (float*)d_out;

  dim3 grid(N_IMG * 64);   // 1024 blocks; block = 8 rows (4 waves x row-pair)
  gabor_conv_kernel<<<grid, dim3(256), 0, stream>>>(img, freq, theta, psi,
                                                    sigma, outp);
}